// Round 4
// baseline (2894.215 us; speedup 1.0000x reference)
//
#include <hip/hip_runtime.h>
#include <cmath>

// VanillaRNN: B=256, T=128, D=1, H=2048, C=10
// R15: R14 sharding (8 groups x 32 blocks, W fp16 in regs, 64 cols x 2048 K
// per block) with the h-exchange moved from MALL-bypassing atomics to
// CACHED plain loads/stores + release/acquire fences. R14 counters showed
// FETCH=1 MB/step (HBM first-touch only) => the 32 MB/step broadcast was
// all MALL-served (atomics bypass L2); MALL read BW was the ~3 us/step
// floor. Now:
//   producer: plain u64 publish stores -> __syncthreads (vmcnt drain: all
//     512 threads' stores are in L2) -> tid0 RELEASE fetch_add on flag
//     (emits buffer_wbl2: writes back ALL dirty L2 lines incl. every
//     thread's publishes, then commits the flag). Flag-visible => data at
//     coherence point, regardless of which thread/wave stored.
//   consumer: relaxed atomic flag polls (bypass => always fresh; unchanged
//     from validated R12 protocol) -> __syncthreads -> per-wave agent
//     ACQUIRE fence (L1+L2 invalidate) -> PLAIN dwordx4 fragment loads.
//     First toucher per line pulls MALL->L2; the other ~31 reads per line
//     on that XCD are L2 hits (~4.3 TB/s/XCD vs shared MALL).
// Correct for ANY block->XCD placement (fences are agent-scope); id%8
// grouping only concentrates the L2 reuse. Overwrite safety transitivity
// unchanged: all 32 group flags(t-1) observed (8 waves x 4) before any
// wave passes the poll-side barrier; publishes of t+1 only after that.
// Also fused: output projection (Sm @ V^T partial + f32 atomicAdd, C==0
// adds bp) into the final step; rnn_out kernel removed.

#define B_ 256
#define T_ 128
#define H_ 2048
#define C_ 10

typedef _Float16 half_t;
typedef _Float16 half8 __attribute__((ext_vector_type(8)));
typedef _Float16 half4v __attribute__((ext_vector_type(4)));
typedef float floatx4 __attribute__((ext_vector_type(4)));
typedef unsigned long long u64;
typedef unsigned long long u64x2 __attribute__((ext_vector_type(2)));

// flag array: dword index  t*(8*32*32) + (g*32 + C)*32  (one 128B line per
// flag). t in [0,127), g in [0,8), C = producer block-in-group [0,32).
#define FLAG_DWORDS (128 * 8 * 32 * 32)   // 4 MB

__device__ __forceinline__ float fast_tanh(float v) {
    return 1.0f - 2.0f / (__expf(2.0f * v) + 1.0f);
}

// ---- persistent RNN kernel: 256 blocks x 512 thr (8 waves, 2/SIMD) ----
__global__ void __launch_bounds__(512, 2) rnn_persist(
    const float* __restrict__ x,   // [B_,T_]
    const float* __restrict__ U,   // [H_]
    const float* __restrict__ W,   // [H_,H_] fp32
    const float* __restrict__ bh,  // [H_]
    const float* __restrict__ V,   // [C_,H_]
    const float* __restrict__ bp,  // [C_]
    half_t* __restrict__ hP0,      // packed state buf 0 (1 MB)
    half_t* __restrict__ hP1,      // packed state buf 1 (1 MB)
    float* __restrict__ hf32,      // d_out h_last region (row-major fp32)
    float* __restrict__ outp,      // d_out projection region [B_,C_] (zeroed)
    unsigned* __restrict__ flags)
{
    const int tid  = threadIdx.x;
    const int wave = tid >> 6, lane = tid & 63;
    const int quad = lane >> 4, lq = lane & 15;
    const int id   = blockIdx.x;
    const int g    = id & 7;                      // group (~XCD under id%8)
    const int C    = id >> 3;                     // block-in-group 0..31
    const int m0   = g * 32;                      // group rows m0..m0+31
    const int n0   = C * 64;                      // block cols n0..n0+63

    // ---- one-time: W frags for this wave's K-range -> regs (fp16) ----
    // wave covers k in [wave*256, wave*256+256); kk = 32-wide k-subchunk
    half8 Bw[8][4];
#pragma unroll
    for (int kk = 0; kk < 8; ++kk) {
#pragma unroll
        for (int nt = 0; nt < 4; ++nt) {
            const int gn = n0 + nt * 16 + lq;
            const int k0 = wave * 256 + kk * 32 + quad * 8;
            const float4 w0 = *(const float4*)&W[(size_t)gn * H_ + k0];
            const float4 w1 = *(const float4*)&W[(size_t)gn * H_ + k0 + 4];
            const float wv[8] = {w0.x, w0.y, w0.z, w0.w, w1.x, w1.y, w1.z, w1.w};
            half8 hw;
#pragma unroll
            for (int j = 0; j < 8; ++j) hw[j] = (half_t)wv[j];
            Bw[kk][nt] = hw;
        }
    }

    // epilogue-owner role: wave w owns output tile (mtO, ntO); 2x4 = 8 tiles
    const int mtO = wave & 1, ntO = wave >> 1;
    const float uvO = U[n0 + ntO * 16 + lq];
    const float bvO = bh[n0 + ntO * 16 + lq];

    __shared__ floatx4 red[2][8][4][64];          // 8-way k-split, 64 KB
    __shared__ float Sm[32][65];                  // epilogue transpose, 8.3 KB
    __shared__ float xs[T_][32];                  // x slab transposed, 16 KB

    for (int i = tid; i < 32 * T_; i += 512) {    // one-time x staging
        const int r = i & 31, tt = i >> 5;
        xs[tt][r] = x[(size_t)(m0 + r) * T_ + tt];
    }
    __syncthreads();

    // producer mapping: thread tid == u64 index in this block's 512-u64
    // region; region layout idx = mt*256 + kc*128 + k8*32 + rlo*2 + q
    //   -> r = (tid>>8)*16 + ((tid>>1)&15)
    //      c = ((tid>>7)&1)*32 + ((tid>>5)&3)*8 + (tid&1)*4
    const int prow = (tid >> 8) * 16 + ((tid >> 1) & 15);   // local row 0..31
    const int pcol = ((tid >> 7) & 1) * 32 + ((tid >> 5) & 3) * 8 + (tid & 1) * 4;
    const size_t slab = (size_t)g * 16384;                  // u64 units (128 KB)
    const size_t pdst = slab + (size_t)C * 512 + tid;
    const size_t cbase = slab + (size_t)wave * 2048 + (size_t)lane * 2;

    // flag addresses
    unsigned* myflag_base = flags + ((size_t)g * 32 + C) * 32;   // + t*8192
    const unsigned* pollp = flags + ((size_t)g * 32 + wave * 4 + (lane & 3)) * 32;

    // ---- step 0: h1 = tanh(x*U + bh) -> packed hP1, signal slot 0 ----
    {
        const float xb = xs[0][prow];
        half4v hv;
#pragma unroll
        for (int j = 0; j < 4; ++j) {
            const int n = n0 + pcol + j;
            hv[j] = (half_t)fast_tanh(xb * U[n] + bh[n]);
        }
        ((u64*)hP1)[pdst] = __builtin_bit_cast(u64, hv);    // plain store
    }
    __syncthreads();              // vmcnt drain: all publishes are in L2
    if (tid == 0)                 // RELEASE: wbl2 (flush dirty L2) + RMW
        __hip_atomic_fetch_add(myflag_base, 1u, __ATOMIC_RELEASE,
                               __HIP_MEMORY_SCOPE_AGENT);

    // ---- steps t = 1..127 ----
    for (int t = 1; t < T_; ++t) {
        const half_t* hin = (t & 1) ? hP1 : hP0;  // h_t (packed)
        half_t* hout      = (t & 1) ? hP0 : hP1;  // h_{t+1} (packed)
        const u64* pw = (const u64*)hin + cbase;

        // wave-level poll: my 4 producers for slot t-1 (relaxed atomic =
        // bypass => always fresh; validated protocol)
        {
            const unsigned* fp = pollp + (size_t)(t - 1) * (8 * 32 * 32);
            while (true) {
                const unsigned v = __hip_atomic_load(fp, __ATOMIC_RELAXED,
                                                     __HIP_MEMORY_SCOPE_AGENT);
                if (__all(v >= 1u)) break;
                __builtin_amdgcn_s_sleep(1);
            }
            asm volatile("" ::: "memory");        // no load hoisting above poll
        }
        __syncthreads();          // all 32 group flags(t-1) observed block-wide
        // ACQUIRE: invalidate L1/L2 so plain loads see the released data
        __builtin_amdgcn_fence(__ATOMIC_ACQUIRE, "agent");

        floatx4 acc[2][4] = {};

        u64 rl[8], rh[8];                         // ring-8 of 16B frags
        auto issue = [&](int f) {
            // f -> (c'=f>>2, mt=(f>>1)&1, kc=f&1)
            const u64* q = pw + (size_t)((f >> 2) * 512 + ((f >> 1) & 1) * 256
                                         + (f & 1) * 128);
            const u64x2 v = *(const u64x2*)q;     // plain dwordx4 (L2-cached)
            rl[f & 7] = v.x;
            rh[f & 7] = v.y;
        };
#pragma unroll
        for (int f = 0; f < 8; ++f) issue(f);
#pragma unroll
        for (int f = 0; f < 16; ++f) {            // 16 A-frags
            const int cp = f >> 2, mt = (f >> 1) & 1, kc = f & 1;
            const int kk = cp * 2 + kc;
            u64x2 bits; bits.x = rl[f & 7]; bits.y = rh[f & 7];
            const half8 av = __builtin_bit_cast(half8, bits);
            if (f + 8 < 16) issue(f + 8);
            acc[mt][0] = __builtin_amdgcn_mfma_f32_16x16x32_f16(av, Bw[kk][0], acc[mt][0], 0, 0, 0);
            acc[mt][1] = __builtin_amdgcn_mfma_f32_16x16x32_f16(av, Bw[kk][1], acc[mt][1], 0, 0, 0);
            acc[mt][2] = __builtin_amdgcn_mfma_f32_16x16x32_f16(av, Bw[kk][2], acc[mt][2], 0, 0, 0);
            acc[mt][3] = __builtin_amdgcn_mfma_f32_16x16x32_f16(av, Bw[kk][3], acc[mt][3], 0, 0, 0);
        }

        // ---- 8-way K-split reduction ----
#pragma unroll
        for (int mt = 0; mt < 2; ++mt)
#pragma unroll
            for (int nt = 0; nt < 4; ++nt)
                red[mt][wave][nt][lane] = acc[mt][nt];
        __syncthreads();

        // owner wave: sum 8 partials, +x*U+bh, tanh -> Sm
        {
            float xr[4];
#pragma unroll
            for (int r = 0; r < 4; ++r) xr[r] = xs[t][mtO * 16 + quad * 4 + r];
            floatx4 s = red[mtO][0][ntO][lane];
#pragma unroll
            for (int ww = 1; ww < 8; ++ww) s += red[mtO][ww][ntO][lane];
#pragma unroll
            for (int r = 0; r < 4; ++r) {
                const float pre = s[r] + xr[r] * uvO + bvO;
                Sm[mtO * 16 + quad * 4 + r][ntO * 16 + lq] = fast_tanh(pre);
            }
        }
        __syncthreads();

        // publish: 1 u64 (4 halfs) per thread into the packed slab (plain)
        {
            float fv[4];
#pragma unroll
            for (int j = 0; j < 4; ++j) fv[j] = Sm[prow][pcol + j];
            half4v hv;
#pragma unroll
            for (int j = 0; j < 4; ++j) hv[j] = (half_t)fv[j];
            ((u64*)hout)[pdst] = __builtin_bit_cast(u64, hv);
            if (t == T_ - 1) {  // final h_128 also to d_out, row-major fp32
                float* fd = hf32 + (size_t)(m0 + prow) * H_ + n0 + pcol;
                *(float4*)fd = make_float4(fv[0], fv[1], fv[2], fv[3]);
            }
        }

        if (t == T_ - 1) {
            // fused output projection: partial out[32,10] = Sm @ V^T (+bp
            // from block C==0), accumulated chip-wide via f32 atomicAdd.
            if (tid < 32 * C_) {
                const int r = tid & 31, c = tid >> 5;    // c in [0,10)
                float s = (C == 0) ? bp[c] : 0.0f;
                const float* vr = V + (size_t)c * H_ + n0;
#pragma unroll 8
                for (int n = 0; n < 64; ++n) s += Sm[r][n] * vr[n];
                atomicAdd(&outp[(size_t)(m0 + r) * C_ + c], s);
            }
        } else {
            __syncthreads();      // vmcnt drain: all publishes are in L2
            if (tid == 0)         // RELEASE: wbl2 + flag RMW
                __hip_atomic_fetch_add(
                    myflag_base + (size_t)t * (8 * 32 * 32), 1u,
                    __ATOMIC_RELEASE, __HIP_MEMORY_SCOPE_AGENT);
        }
    }
}

extern "C" void kernel_launch(void* const* d_in, const int* in_sizes, int n_in,
                              void* d_out, int out_size, void* d_ws, size_t ws_size,
                              hipStream_t stream) {
    const float* x  = (const float*)d_in[0];
    const float* U  = (const float*)d_in[1];
    const float* W  = (const float*)d_in[2];
    const float* V  = (const float*)d_in[3];
    const float* bh = (const float*)d_in[4];
    const float* bp = (const float*)d_in[5];

    float* out_h = (float*)d_out;                 // [B_*H_] fp32 h_last
    float* outp  = out_h + (size_t)B_ * H_;       // [B_*C_]

    half_t* hP0 = (half_t*)d_ws;                                   // 1 MB packed
    half_t* hP1 = hP0 + (size_t)B_ * H_;                           // 1 MB packed
    unsigned* flags = (unsigned*)((char*)d_ws + 2u * 1024 * 1024); // 4 MB

    hipMemsetAsync(flags, 0, FLAG_DWORDS * sizeof(unsigned), stream);
    hipMemsetAsync(outp, 0, (size_t)B_ * C_ * sizeof(float), stream);

    rnn_persist<<<dim3(256), dim3(512), 0, stream>>>(
        x, U, W, bh, V, bp, hP0, hP1, out_h, outp, flags);
}

// Round 5
// 666.305 us; speedup vs baseline: 4.3437x; 4.3437x over previous
//
#include <hip/hip_runtime.h>
#include <cmath>

// VanillaRNN: B=256, T=128, D=1, H=2048, C=10
// R16: revert R15's cached+fenced exchange (catastrophic: per-step agent
// release/acquire = whole-L2 wbl2/inv per block per step -> 2885 us) back
// to the VALIDATED R14 protocol (622 us): atomic-exchange publishes
// (commit+allocate at MALL; returned value kept live), __syncthreads vmcnt
// drain proves global visibility, single RELAXED flag RMW, consumers poll
// v>=1 with relaxed atomic loads (bypass => fresh), relaxed atomic u64
// fragment loads (MALL-served).
// R16 deltas vs R14, both low-risk:
//   1. rnn_out FUSED into the final step (R15-validated projection logic:
//      partial Sm @ V^T + f32 atomicAdd, C==0 adds bp) -> one launch.
//   2. fragment-load pipeline deepened 8 -> 16: all 32 atomic loads issued
//      before the MFMA loop (R14's ring-8 left the last loads' MALL
//      latency exposed). +16 VGPR, still under the 256/wave cliff.
//   3. dead t=127 slab publish skipped (h_128 never consumed).
// Geometry/protocol unchanged: 8 groups (g=id&7, rows m0=g*32..+32) x 32
// blocks (C=id>>3, cols n0=C*64..+64); W fp16 in 128 VGPRs; 8-way K-split;
// wave w polls its 4 producers (4w..4w+3) for slot t-1; overwrite safety
// transitive through the pre-reduction __syncthreads.

#define B_ 256
#define T_ 128
#define H_ 2048
#define C_ 10

typedef _Float16 half_t;
typedef _Float16 half8 __attribute__((ext_vector_type(8)));
typedef _Float16 half4v __attribute__((ext_vector_type(4)));
typedef float floatx4 __attribute__((ext_vector_type(4)));
typedef unsigned long long u64;
typedef unsigned long long u64x2 __attribute__((ext_vector_type(2)));

// flag array: dword index  t*(8*32*32) + (g*32 + C)*32  (one 128B line per
// flag). t in [0,127), g in [0,8), C = producer block-in-group [0,32).
#define FLAG_DWORDS (128 * 8 * 32 * 32)   // 4 MB

__device__ __forceinline__ float fast_tanh(float v) {
    return 1.0f - 2.0f / (__expf(2.0f * v) + 1.0f);
}

// publish one u64 of packed halfs via RMW (commits+allocates at MALL; the
// returned old value is kept live so the swap cannot be demoted to a
// posted store)
__device__ __forceinline__ void publish_u64(u64* p, u64 v) {
    u64 old = __hip_atomic_exchange(p, v, __ATOMIC_RELAXED,
                                    __HIP_MEMORY_SCOPE_AGENT);
    asm volatile("" :: "v"(old));
}

// ---- persistent RNN kernel: 256 blocks x 512 thr (8 waves, 2/SIMD) ----
__global__ void __launch_bounds__(512, 2) rnn_persist(
    const float* __restrict__ x,   // [B_,T_]
    const float* __restrict__ U,   // [H_]
    const float* __restrict__ W,   // [H_,H_] fp32
    const float* __restrict__ bh,  // [H_]
    const float* __restrict__ V,   // [C_,H_]
    const float* __restrict__ bp,  // [C_]
    half_t* __restrict__ hP0,      // packed state buf 0 (1 MB)
    half_t* __restrict__ hP1,      // packed state buf 1 (1 MB)
    float* __restrict__ hf32,      // d_out h_last region (row-major fp32)
    float* __restrict__ outp,      // d_out projection region [B_,C_] (zeroed)
    unsigned* __restrict__ flags)
{
    const int tid  = threadIdx.x;
    const int wave = tid >> 6, lane = tid & 63;
    const int quad = lane >> 4, lq = lane & 15;
    const int id   = blockIdx.x;
    const int g    = id & 7;                      // group (~XCD under id%8)
    const int C    = id >> 3;                     // block-in-group 0..31
    const int m0   = g * 32;                      // group rows m0..m0+31
    const int n0   = C * 64;                      // block cols n0..n0+63

    // ---- one-time: W frags for this wave's K-range -> regs (fp16) ----
    // wave covers k in [wave*256, wave*256+256); kk = 32-wide k-subchunk
    half8 Bw[8][4];
#pragma unroll
    for (int kk = 0; kk < 8; ++kk) {
#pragma unroll
        for (int nt = 0; nt < 4; ++nt) {
            const int gn = n0 + nt * 16 + lq;
            const int k0 = wave * 256 + kk * 32 + quad * 8;
            const float4 w0 = *(const float4*)&W[(size_t)gn * H_ + k0];
            const float4 w1 = *(const float4*)&W[(size_t)gn * H_ + k0 + 4];
            const float wv[8] = {w0.x, w0.y, w0.z, w0.w, w1.x, w1.y, w1.z, w1.w};
            half8 hw;
#pragma unroll
            for (int j = 0; j < 8; ++j) hw[j] = (half_t)wv[j];
            Bw[kk][nt] = hw;
        }
    }

    // epilogue-owner role: wave w owns output tile (mtO, ntO); 2x4 = 8 tiles
    const int mtO = wave & 1, ntO = wave >> 1;
    const float uvO = U[n0 + ntO * 16 + lq];
    const float bvO = bh[n0 + ntO * 16 + lq];

    __shared__ floatx4 red[2][8][4][64];          // 8-way k-split, 64 KB
    __shared__ float Sm[32][65];                  // epilogue transpose, 8.3 KB
    __shared__ float xs[T_][32];                  // x slab transposed, 16 KB

    for (int i = tid; i < 32 * T_; i += 512) {    // one-time x staging
        const int r = i & 31, tt = i >> 5;
        xs[tt][r] = x[(size_t)(m0 + r) * T_ + tt];
    }
    __syncthreads();

    // producer mapping: thread tid == u64 index in this block's 512-u64
    // region; region layout idx = mt*256 + kc*128 + k8*32 + rlo*2 + q
    //   -> r = (tid>>8)*16 + ((tid>>1)&15)
    //      c = ((tid>>7)&1)*32 + ((tid>>5)&3)*8 + (tid&1)*4
    const int prow = (tid >> 8) * 16 + ((tid >> 1) & 15);   // local row 0..31
    const int pcol = ((tid >> 7) & 1) * 32 + ((tid >> 5) & 3) * 8 + (tid & 1) * 4;
    const size_t slab = (size_t)g * 16384;                  // u64 units (128 KB)
    const size_t pdst = slab + (size_t)C * 512 + tid;
    const size_t cbase = slab + (size_t)wave * 2048 + (size_t)lane * 2;

    // flag addresses
    unsigned* myflag_base = flags + ((size_t)g * 32 + C) * 32;   // + t*8192
    const unsigned* pollp = flags + ((size_t)g * 32 + wave * 4 + (lane & 3)) * 32;

    // ---- step 0: h1 = tanh(x*U + bh) -> packed hP1, signal slot 0 ----
    {
        const float xb = xs[0][prow];
        half4v hv;
#pragma unroll
        for (int j = 0; j < 4; ++j) {
            const int n = n0 + pcol + j;
            hv[j] = (half_t)fast_tanh(xb * U[n] + bh[n]);
        }
        publish_u64((u64*)hP1 + pdst, __builtin_bit_cast(u64, hv));
    }
    __syncthreads();          // drains vmcnt: all exchanges committed at MALL
    if (tid == 0)
        __hip_atomic_fetch_add(myflag_base, 1u, __ATOMIC_RELAXED,
                               __HIP_MEMORY_SCOPE_AGENT);

    // ---- steps t = 1..127 ----
    for (int t = 1; t < T_; ++t) {
        const half_t* hin = (t & 1) ? hP1 : hP0;  // h_t (packed)
        half_t* hout      = (t & 1) ? hP0 : hP1;  // h_{t+1} (packed)
        const u64* pw = (const u64*)hin + cbase;

        // wave-level poll: my 4 producers for slot t-1 (v >= 1; the flag RMW
        // is issued only after all of that producer's data RMWs committed)
        {
            const unsigned* fp = pollp + (size_t)(t - 1) * (8 * 32 * 32);
            while (true) {
                const unsigned v = __hip_atomic_load(fp, __ATOMIC_RELAXED,
                                                     __HIP_MEMORY_SCOPE_AGENT);
                if (__all(v >= 1u)) break;
                __builtin_amdgcn_s_sleep(1);
            }
            asm volatile("" ::: "memory");        // no load hoisting above poll
        }

        floatx4 acc[2][4] = {};

        u64 rl[16], rh[16];                       // all 16 frags, 16-deep
        auto issue = [&](int f) {
            // f -> (c'=f>>2, mt=(f>>1)&1, kc=f&1)
            const u64* q = pw + (size_t)((f >> 2) * 512 + ((f >> 1) & 1) * 256
                                         + (f & 1) * 128);
            rl[f] = __hip_atomic_load(q, __ATOMIC_RELAXED,
                                      __HIP_MEMORY_SCOPE_AGENT);
            rh[f] = __hip_atomic_load(q + 1, __ATOMIC_RELAXED,
                                      __HIP_MEMORY_SCOPE_AGENT);
        };
#pragma unroll
        for (int f = 0; f < 16; ++f) issue(f);    // issue ALL before MFMA
#pragma unroll
        for (int f = 0; f < 16; ++f) {            // 16 A-frags
            const int cp = f >> 2, mt = (f >> 1) & 1, kc = f & 1;
            const int kk = cp * 2 + kc;
            u64x2 bits; bits.x = rl[f]; bits.y = rh[f];
            const half8 av = __builtin_bit_cast(half8, bits);
            acc[mt][0] = __builtin_amdgcn_mfma_f32_16x16x32_f16(av, Bw[kk][0], acc[mt][0], 0, 0, 0);
            acc[mt][1] = __builtin_amdgcn_mfma_f32_16x16x32_f16(av, Bw[kk][1], acc[mt][1], 0, 0, 0);
            acc[mt][2] = __builtin_amdgcn_mfma_f32_16x16x32_f16(av, Bw[kk][2], acc[mt][2], 0, 0, 0);
            acc[mt][3] = __builtin_amdgcn_mfma_f32_16x16x32_f16(av, Bw[kk][3], acc[mt][3], 0, 0, 0);
        }

        // ---- 8-way K-split reduction ----
#pragma unroll
        for (int mt = 0; mt < 2; ++mt)
#pragma unroll
            for (int nt = 0; nt < 4; ++nt)
                red[mt][wave][nt][lane] = acc[mt][nt];
        __syncthreads();

        // owner wave: sum 8 partials, +x*U+bh, tanh -> Sm
        {
            float xr[4];
#pragma unroll
            for (int r = 0; r < 4; ++r) xr[r] = xs[t][mtO * 16 + quad * 4 + r];
            floatx4 s = red[mtO][0][ntO][lane];
#pragma unroll
            for (int ww = 1; ww < 8; ++ww) s += red[mtO][ww][ntO][lane];
#pragma unroll
            for (int r = 0; r < 4; ++r) {
                const float pre = s[r] + xr[r] * uvO + bvO;
                Sm[mtO * 16 + quad * 4 + r][ntO * 16 + lq] = fast_tanh(pre);
            }
        }
        __syncthreads();

        if (t < T_ - 1) {
            // publish: 1 u64 (4 halfs) per thread into the packed slab (RMW)
            float fv[4];
#pragma unroll
            for (int j = 0; j < 4; ++j) fv[j] = Sm[prow][pcol + j];
            half4v hv;
#pragma unroll
            for (int j = 0; j < 4; ++j) hv[j] = (half_t)fv[j];
            publish_u64((u64*)hout + pdst, __builtin_bit_cast(u64, hv));
            __syncthreads();      // drains vmcnt: exchanges committed at MALL
            if (tid == 0)
                __hip_atomic_fetch_add(
                    myflag_base + (size_t)t * (8 * 32 * 32), 1u,
                    __ATOMIC_RELAXED, __HIP_MEMORY_SCOPE_AGENT);
        } else {
            // final step: h_128 -> d_out fp32 (no slab publish: dead)
            {
                float fv[4];
#pragma unroll
                for (int j = 0; j < 4; ++j) fv[j] = Sm[prow][pcol + j];
                float* fd = hf32 + (size_t)(m0 + prow) * H_ + n0 + pcol;
                *(float4*)fd = make_float4(fv[0], fv[1], fv[2], fv[3]);
            }
            // fused output projection: partial out[32,10] = Sm @ V^T (+bp
            // from block C==0), accumulated chip-wide via f32 atomicAdd.
            if (tid < 32 * C_) {
                const int r = tid & 31, c = tid >> 5;    // c in [0,10)
                float s = (C == 0) ? bp[c] : 0.0f;
                const float* vr = V + (size_t)c * H_ + n0;
#pragma unroll 8
                for (int n = 0; n < 64; ++n) s += Sm[r][n] * vr[n];
                atomicAdd(&outp[(size_t)(m0 + r) * C_ + c], s);
            }
        }
    }
}

extern "C" void kernel_launch(void* const* d_in, const int* in_sizes, int n_in,
                              void* d_out, int out_size, void* d_ws, size_t ws_size,
                              hipStream_t stream) {
    const float* x  = (const float*)d_in[0];
    const float* U  = (const float*)d_in[1];
    const float* W  = (const float*)d_in[2];
    const float* V  = (const float*)d_in[3];
    const float* bh = (const float*)d_in[4];
    const float* bp = (const float*)d_in[5];

    float* out_h = (float*)d_out;                 // [B_*H_] fp32 h_last
    float* outp  = out_h + (size_t)B_ * H_;       // [B_*C_]

    half_t* hP0 = (half_t*)d_ws;                                   // 1 MB packed
    half_t* hP1 = hP0 + (size_t)B_ * H_;                           // 1 MB packed
    unsigned* flags = (unsigned*)((char*)d_ws + 2u * 1024 * 1024); // 4 MB

    hipMemsetAsync(flags, 0, FLAG_DWORDS * sizeof(unsigned), stream);
    hipMemsetAsync(outp, 0, (size_t)B_ * C_ * sizeof(float), stream);

    rnn_persist<<<dim3(256), dim3(512), 0, stream>>>(
        x, U, W, bh, V, bp, hP0, hP1, out_h, outp, flags);
}